// Round 5
// baseline (206.192 us; speedup 1.0000x reference)
//
#include <hip/hip_runtime.h>

typedef short  bf16x8  __attribute__((ext_vector_type(8)));
typedef float  f32x4   __attribute__((ext_vector_type(4)));
typedef float  f32x16  __attribute__((ext_vector_type(16)));
typedef unsigned short ushort;
typedef unsigned short u16x4 __attribute__((ext_vector_type(4)));

__device__ __forceinline__ ushort f2bf(float f) {
  __bf16 h = (__bf16)f;                 // RNE
  return (ushort)__builtin_bit_cast(unsigned short, h);
}

// ws layout (float offsets):
//   [0        .. 4194304)  gate partials: ks*524288 + b*8192 + gate*2048 + j   (ks 0..7)
//   [4194304  .. 5242880)  y partials:    4194304 + ksy*131072 + b*2048 + j    (ksy 0..7)
//   [5242880  .. )         Abf: bf16 [64][4096] = 262144 ushorts (h | x concat)
#define GATE_PART 0
#define Y_PART    4194304
#define ABF_OFF   5242880
#define WBUF      8448        // 64 rows x 132 ushorts (264 B row stride)

// ---------------------------------------------------------------------------
// Kernel 0: convert A = [h_prev | x] to bf16, row-major [64][4096].
// ---------------------------------------------------------------------------
__global__ __launch_bounds__(256) void lstm_aconv(
    const float* __restrict__ X, const float* __restrict__ H,
    ushort* __restrict__ Abf)
{
  const int t  = blockIdx.x * 256 + threadIdx.x;   // 32768 threads
  const int e0 = t * 8;
  const int b  = e0 >> 12;
  const int k  = e0 & 4095;
  const float* src = (k < 2048) ? (H + (size_t)b * 2048 + k)
                                : (X + (size_t)b * 2048 + (k - 2048));
  f32x4 v0 = *(const f32x4*)(src);
  f32x4 v1 = *(const f32x4*)(src + 4);
  bf16x8 o;
  o[0] = (short)f2bf(v0[0]); o[1] = (short)f2bf(v0[1]);
  o[2] = (short)f2bf(v0[2]); o[3] = (short)f2bf(v0[3]);
  o[4] = (short)f2bf(v1[0]); o[5] = (short)f2bf(v1[1]);
  o[6] = (short)f2bf(v1[2]); o[7] = (short)f2bf(v1[3]);
  *(bf16x8*)(Abf + e0) = o;
}

// ---------------------------------------------------------------------------
// Per-block skinny GEMM job: C[64 x 128cols] over K = NCH*64.
// W: global f32 -> VGPR (dwordx4, the proven streaming path) -> cvt bf16 ->
//    ds_write_b64 into double-buffered LDS [64][132] (row stride 264 B:
//    fragment reads hit 32 distinct banks, conflict-free).
// A: bf16 fragments straight from global (L2-resident), per-lane 16 B loads.
// One __syncthreads per chunk. sched_barrier(0) fences keep the W loads
// issued early (defeats the R3 load-sinking failure).
// ---------------------------------------------------------------------------
template<int NCH>
__device__ __forceinline__ void gemm_job(
    const float* __restrict__ Wm, int krow0,
    const ushort* __restrict__ Ap0,
    float bias, float* __restrict__ outBase, int outStride,
    ushort* __restrict__ ldsW, int lane, int widx)
{
  const int n    = lane & 31;
  const int kg8  = (lane >> 5) << 3;
  const int rsub = widx * 2 + (lane >> 5);   // sub-row within each 8-row group
  const int c0   = (lane & 31) * 4;          // 4-col quad within 128-stripe
  const int j0w  = widx * 32;                // wave's col offset
  const ushort* Ap1 = Ap0 + (size_t)32 * 4096;

  f32x16 acc0, acc1;
  #pragma unroll
  for (int r = 0; r < 16; ++r) { acc0[r] = bias; acc1[r] = bias; }

  // prologue: stage chunk 0 into buf 0
  {
    f32x4 w[8];
    #pragma unroll
    for (int i = 0; i < 8; ++i)
      w[i] = *(const f32x4*)(Wm + (size_t)(krow0 + i * 8 + rsub) * 2048 + c0);
    #pragma unroll
    for (int i = 0; i < 8; ++i) {
      u16x4 u;
      #pragma unroll
      for (int j = 0; j < 4; ++j) u[j] = f2bf(w[i][j]);
      *(u16x4*)(ldsW + (i * 8 + rsub) * 132 + c0) = u;
    }
    __syncthreads();
  }

  #pragma unroll
  for (int ch = 0; ch < NCH; ++ch) {
    const ushort* lw = ldsW + (ch & 1) * WBUF;

    // A fragments for chunk ch — issued FIRST (oldest in vmcnt order, so
    // compute's A-waits never drain the younger W prefetch stream).
    bf16x8 a0[4], a1[4];
    #pragma unroll
    for (int k0 = 0; k0 < 4; ++k0) {
      a0[k0] = *(const bf16x8*)(Ap0 + ch * 64 + k0 * 16 + kg8);
      a1[k0] = *(const bf16x8*)(Ap1 + ch * 64 + k0 * 16 + kg8);
    }
    __builtin_amdgcn_sched_barrier(0);

    // W prefetch for chunk ch+1 (in flight across the whole compute phase)
    f32x4 w[8];
    if (ch + 1 < NCH) {
      #pragma unroll
      for (int i = 0; i < 8; ++i)
        w[i] = *(const f32x4*)(Wm + (size_t)(krow0 + (ch + 1) * 64 + i * 8 + rsub) * 2048 + c0);
    }
    __builtin_amdgcn_sched_barrier(0);

    // compute chunk ch: 4 K-steps of 16
    #pragma unroll
    for (int k0 = 0; k0 < 4; ++k0) {
      const int kk = k0 * 16 + kg8;
      bf16x8 bfrag;
      #pragma unroll
      for (int i = 0; i < 8; ++i)
        bfrag[i] = (short)lw[(kk + i) * 132 + j0w + n];
      acc0 = __builtin_amdgcn_mfma_f32_32x32x16_bf16(a0[k0], bfrag, acc0, 0, 0, 0);
      acc1 = __builtin_amdgcn_mfma_f32_32x32x16_bf16(a1[k0], bfrag, acc1, 0, 0, 0);
    }
    __builtin_amdgcn_sched_barrier(0);

    // write chunk ch+1 into the other buffer, one barrier per chunk
    if (ch + 1 < NCH) {
      ushort* dst = ldsW + ((ch & 1) ^ 1) * WBUF;
      #pragma unroll
      for (int i = 0; i < 8; ++i) {
        u16x4 u;
        #pragma unroll
        for (int j = 0; j < 4; ++j) u[j] = f2bf(w[i][j]);
        *(u16x4*)(dst + (i * 8 + rsub) * 132 + c0) = u;
      }
      __syncthreads();
    }
  }

  // D layout (32x32): col = lane&31, row = (r&3) + 8*(r>>2) + 4*(lane>>5)
  const int rbase = 4 * (lane >> 5);
  #pragma unroll
  for (int r = 0; r < 16; ++r) {
    const int row = (r & 3) + 8 * (r >> 2) + rbase;
    outBase[(size_t)row * outStride]        = acc0[r];
    outBase[(size_t)(row + 32) * outStride] = acc1[r];
  }
}

// ---------------------------------------------------------------------------
// Kernel 1: 640 blocks x 256 thr (4 waves), all co-resident (4 blocks/CU).
//   bid < 512 : gate job. gate=bid>>7, stripe=(bid>>3)&15, ks=bid&7. K=512.
//   bid >= 512: y job.    stripe=(yi>>3), ksy=yi&7.                  K=256.
// ---------------------------------------------------------------------------
__global__ __launch_bounds__(256, 4) void lstm_gemm(
    const float* __restrict__ Wfh, const float* __restrict__ Wfx, const float* __restrict__ bfp,
    const float* __restrict__ Wih, const float* __restrict__ Wix, const float* __restrict__ bip,
    const float* __restrict__ Woh, const float* __restrict__ Wox, const float* __restrict__ bop,
    const float* __restrict__ Wch, const float* __restrict__ Wcx, const float* __restrict__ bcp,
    const float* __restrict__ Wy,  const float* __restrict__ by,
    float* __restrict__ ws)
{
  __shared__ ushort ldsW[2 * WBUF];      // 33 KB -> 4 blocks/CU

  const int tid  = threadIdx.x;
  const int lane = tid & 63;
  const int widx = tid >> 6;
  const int n    = lane & 31;
  const int j0w  = widx * 32;
  const ushort* Abf = (const ushort*)(ws + ABF_OFF);
  const int bid = blockIdx.x;

  if (bid < 512) {
    const int gate   = bid >> 7;
    const int stripe = (bid >> 3) & 15;
    const int ks     = bid & 7;
    const int j0     = stripe * 128;
    const float *Wg_h, *Wg_x, *bg;
    if      (gate == 0) { Wg_h = Wfh; Wg_x = Wfx; bg = bfp; }
    else if (gate == 1) { Wg_h = Wih; Wg_x = Wix; bg = bip; }
    else if (gate == 2) { Wg_h = Wch; Wg_x = Wcx; bg = bcp; }
    else                { Wg_h = Woh; Wg_x = Wox; bg = bop; }
    const float* Wm  = ((ks < 4) ? Wg_h : Wg_x) + j0;
    const int krow0  = (ks & 3) * 512;
    const int aK0    = ks * 512;
    const float bias = (ks == 0) ? bg[j0 + j0w + n] : 0.f;
    float* outBase = ws + GATE_PART + (size_t)ks * 524288 + (size_t)gate * 2048 + j0 + j0w + n;
    const ushort* Ap0 = Abf + (size_t)n * 4096 + aK0;
    gemm_job<8>(Wm, krow0, Ap0, bias, outBase, 8192, ldsW, lane, widx);
  } else {
    const int yi     = bid - 512;
    const int stripe = yi >> 3;
    const int ksy    = yi & 7;
    const int j0     = stripe * 128;
    const float* Wm  = Wy + j0;
    const int krow0  = ksy * 256;
    const float bias = (ksy == 0) ? by[j0 + j0w + n] : 0.f;
    float* outBase = ws + Y_PART + (size_t)ksy * 131072 + j0 + j0w + n;
    const ushort* Ap0 = Abf + (size_t)n * 4096 + krow0;   // y uses h region
    gemm_job<4>(Wm, krow0, Ap0, bias, outBase, 2048, ldsW, lane, widx);
  }
}

// ---------------------------------------------------------------------------
// Kernel 2: reduce K-split partials, apply LSTM nonlinearity, pack [y|h|c].
// ---------------------------------------------------------------------------
__device__ __forceinline__ float fsigmoid(float x) {
  return 1.f / (1.f + __expf(-x));
}
__device__ __forceinline__ float ftanh(float x) {
  return 1.f - 2.f / (1.f + __expf(2.f * x));
}

__global__ __launch_bounds__(64) void lstm_combine(
    const float* __restrict__ ws, const float* __restrict__ c_prev,
    float* __restrict__ out)
{
  const int t  = blockIdx.x * 64 + threadIdx.x;  // 0..32767
  const int b  = t >> 9;
  const int j4 = (t & 511) * 4;

  f32x4 g[4];
  #pragma unroll
  for (int gg = 0; gg < 4; ++gg) {
    f32x4 s = (f32x4){0.f, 0.f, 0.f, 0.f};
    #pragma unroll
    for (int ks = 0; ks < 8; ++ks)
      s += *(const f32x4*)(ws + GATE_PART + (size_t)ks * 524288 + (size_t)b * 8192 + gg * 2048 + j4);
    g[gg] = s;
  }
  f32x4 ysum = (f32x4){0.f, 0.f, 0.f, 0.f};
  #pragma unroll
  for (int ks = 0; ks < 8; ++ks)
    ysum += *(const f32x4*)(ws + Y_PART + (size_t)ks * 131072 + (size_t)b * 2048 + j4);

  const f32x4 cp = *(const f32x4*)(c_prev + (size_t)b * 2048 + j4);
  f32x4 hF, cF;
  #pragma unroll
  for (int e = 0; e < 4; ++e) {
    float f  = fsigmoid(g[0][e]);
    float i  = fsigmoid(g[1][e]);
    float ct = ftanh(g[2][e]);
    float o  = fsigmoid(g[3][e]);
    float c  = f * cp[e] + i * ct;
    cF[e] = c;
    hF[e] = o * ftanh(c);
  }
  float* ob = out + (size_t)b * 6144;
  *(f32x4*)(ob + j4)        = ysum;   // y = h_prev @ Wy + by
  *(f32x4*)(ob + 2048 + j4) = hF;     // h
  *(f32x4*)(ob + 4096 + j4) = cF;     // c
}

extern "C" void kernel_launch(void* const* d_in, const int* in_sizes, int n_in,
                              void* d_out, int out_size, void* d_ws, size_t ws_size,
                              hipStream_t stream)
{
  const float* X   = (const float*)d_in[0];
  const float* H   = (const float*)d_in[1];
  const float* Cp  = (const float*)d_in[2];
  const float* Wfh = (const float*)d_in[3];
  const float* Wfx = (const float*)d_in[4];
  const float* bfp = (const float*)d_in[5];
  const float* Wih = (const float*)d_in[6];
  const float* Wix = (const float*)d_in[7];
  const float* bip = (const float*)d_in[8];
  const float* Woh = (const float*)d_in[9];
  const float* Wox = (const float*)d_in[10];
  const float* bop = (const float*)d_in[11];
  const float* Wch = (const float*)d_in[12];
  const float* Wcx = (const float*)d_in[13];
  const float* bcp = (const float*)d_in[14];
  const float* Wy  = (const float*)d_in[15];
  const float* by  = (const float*)d_in[16];
  float* ws  = (float*)d_ws;
  float* out = (float*)d_out;

  lstm_aconv<<<128, 256, 0, stream>>>(X, H, (ushort*)(ws + ABF_OFF));
  lstm_gemm<<<640, 256, 0, stream>>>(Wfh, Wfx, bfp, Wih, Wix, bip,
                                     Woh, Wox, bop, Wch, Wcx, bcp, Wy, by, ws);
  lstm_combine<<<512, 64, 0, stream>>>(ws, Cp, out);
}

// Round 6
// 204.900 us; speedup vs baseline: 1.0063x; 1.0063x over previous
//
#include <hip/hip_runtime.h>

#define GAS __attribute__((address_space(1)))
#define LAS __attribute__((address_space(3)))

typedef short  bf16x8  __attribute__((ext_vector_type(8)));
typedef float  f32x4   __attribute__((ext_vector_type(4)));
typedef float  f32x16  __attribute__((ext_vector_type(16)));
typedef unsigned short ushort;

__device__ __forceinline__ ushort f2bf(float f) {
  __bf16 h = (__bf16)f;                 // RNE
  return __builtin_bit_cast(unsigned short, h);
}

// ws layout (float offsets):
//   [0        .. 4194304)  gate partials: ks*524288 + b*8192 + gate*2048 + j   (ks 0..7)
//   [4194304  .. 5242880)  y partials:    4194304 + ksy*131072 + b*2048 + j    (ksy 0..7)
//   [5242880  .. )         Abf: bf16 [64][4096] = 262144 ushorts (h | x concat)
#define GATE_PART 0
#define Y_PART    4194304
#define ABF_OFF   5242880

// ---------------------------------------------------------------------------
// Kernel 0: convert A = [h_prev | x] to bf16, row-major [64][4096].
// ---------------------------------------------------------------------------
__global__ __launch_bounds__(256) void lstm_aconv(
    const float* __restrict__ X, const float* __restrict__ H,
    ushort* __restrict__ Abf)
{
  const int t  = blockIdx.x * 256 + threadIdx.x;   // 32768 threads
  const int e0 = t * 8;
  const int b  = e0 >> 12;
  const int k  = e0 & 4095;
  const float* src = (k < 2048) ? (H + (size_t)b * 2048 + k)
                                : (X + (size_t)b * 2048 + (k - 2048));
  f32x4 v0 = *(const f32x4*)(src);
  f32x4 v1 = *(const f32x4*)(src + 4);
  bf16x8 o;
  o[0] = (short)f2bf(v0[0]); o[1] = (short)f2bf(v0[1]);
  o[2] = (short)f2bf(v0[2]); o[3] = (short)f2bf(v0[3]);
  o[4] = (short)f2bf(v1[0]); o[5] = (short)f2bf(v1[1]);
  o[6] = (short)f2bf(v1[2]); o[7] = (short)f2bf(v1[3]);
  *(bf16x8*)(Abf + e0) = o;
}

// ---------------------------------------------------------------------------
// Kernel 1: LDS-staged skinny GEMM, ring-4 / depth-3 global_load_lds pipeline.
// 512 blocks x 256 thr (4 waves) = exactly 2 blocks/CU, one dispatch round.
//   every block: 16 gate chunks (BK=32) of C_gate[64 x 128cols], K=512 slice.
//   blocks 0..127: +8 y chunks (Wy), K=256 slice, same 128-col stripe.
// Per chunk per wave: 4 W global_load_lds (16 KB/blk) + 1 A (4 KB/blk).
// vmcnt ladder: 15 steady (3 chunks in flight) -> 10 -> 5 -> 0 drain.
// ---------------------------------------------------------------------------
template<int NCC>
__device__ __forceinline__ void gemm_job(
    const float* __restrict__ Wg,  int krow0g, int aK0g,
    const float* __restrict__ Wyb, int yk0,
    float biasG, float biasY,
    float* __restrict__ outG, float* __restrict__ outY,
    const ushort* __restrict__ Abf,
    float* __restrict__ ldsW, ushort* __restrict__ ldsA,
    int lane, int widx)
{
  const int n   = lane & 31;
  const int kg8 = (lane >> 5) << 3;
  const int j0w = widx * 32;

  // --- stage chunk cc into ring buffer cc&3 (5 global_load_lds / wave) ---
  auto stage = [&](int cc) {
    const int buf = cc & 3;
    const float* wsM; int krow, aK;
    if (cc < 16) { wsM = Wg;  krow = krow0g + cc * 32;        aK = aK0g + cc * 32; }
    else         { wsM = Wyb; krow = yk0 + (cc - 16) * 32;    aK = yk0  + (cc - 16) * 32; }
    #pragma unroll
    for (int i = 0; i < 4; ++i) {      // W: rows (i*8 + widx*2 + lane>>5), 128 f32/row
      const float* src = wsM + (size_t)(krow + i * 8 + widx * 2 + (lane >> 5)) * 2048
                             + (lane & 31) * 4;
      float* dst = ldsW + (size_t)buf * 4096 + (i * 8 + widx * 2) * 128;
      __builtin_amdgcn_global_load_lds((const GAS unsigned*)src,
                                       (LAS unsigned*)dst, 16, 0, 0);
    }
    {                                   // A: rows widx*16..+16, 32 bf16/row
      const ushort* src = Abf + (size_t)(widx * 16 + (lane >> 2)) * 4096 + aK
                              + (lane & 3) * 8;
      ushort* dst = ldsA + (size_t)buf * 2048 + widx * 16 * 32;
      __builtin_amdgcn_global_load_lds((const GAS unsigned*)src,
                                       (LAS unsigned*)dst, 16, 0, 0);
    }
  };

  f32x16 acc0, acc1;
  #pragma unroll
  for (int r = 0; r < 16; ++r) { acc0[r] = biasG; acc1[r] = biasG; }

  auto writeOut = [&](float* base, int stride) {
    const int rbase = 4 * (lane >> 5);
    #pragma unroll
    for (int r = 0; r < 16; ++r) {      // D: col=lane&31, row=(r&3)+8*(r>>2)+rbase
      const int row = (r & 3) + 8 * (r >> 2) + rbase;
      base[(size_t)row * stride]        = acc0[r];
      base[(size_t)(row + 32) * stride] = acc1[r];
    }
  };

  stage(0); stage(1); stage(2);          // depth-3 prologue (15 in flight)

  #pragma unroll
  for (int cc = 0; cc < NCC; ++cc) {
    if (cc + 3 < NCC) stage(cc + 3);
    const int rem = NCC - 1 - cc;        // chunks allowed to stay in flight
    if      (rem >= 3) asm volatile("s_waitcnt vmcnt(15)" ::: "memory");
    else if (rem == 2) asm volatile("s_waitcnt vmcnt(10)" ::: "memory");
    else if (rem == 1) asm volatile("s_waitcnt vmcnt(5)"  ::: "memory");
    else               asm volatile("s_waitcnt vmcnt(0)"  ::: "memory");
    __builtin_amdgcn_s_barrier();        // chunk cc visible block-wide

    {  // compute chunk cc: 2 K-steps of 16
      const float*  lw = ldsW + (size_t)(cc & 3) * 4096;
      const ushort* la = ldsA + (size_t)(cc & 3) * 2048;
      #pragma unroll
      for (int k0 = 0; k0 < 32; k0 += 16) {
        const int kk = k0 + kg8;
        float wf[8];
        #pragma unroll
        for (int i = 0; i < 8; ++i)
          wf[i] = lw[(kk + i) * 128 + j0w + n];     // conflict-free (32 consec banks)
        bf16x8 bfrag;
        #pragma unroll
        for (int i = 0; i < 8; ++i) bfrag[i] = (short)f2bf(wf[i]);
        bf16x8 a0 = *(const bf16x8*)(la + (size_t)n * 32 + kk);
        bf16x8 a1 = *(const bf16x8*)(la + (size_t)(n + 32) * 32 + kk);
        acc0 = __builtin_amdgcn_mfma_f32_32x32x16_bf16(a0, bfrag, acc0, 0, 0, 0);
        acc1 = __builtin_amdgcn_mfma_f32_32x32x16_bf16(a1, bfrag, acc1, 0, 0, 0);
      }
    }
    if (NCC > 16 && cc == 15) {          // gate part done; switch to y accumulation
      writeOut(outG, 8192);
      #pragma unroll
      for (int r = 0; r < 16; ++r) { acc0[r] = biasY; acc1[r] = biasY; }
    }
    __builtin_amdgcn_s_barrier();        // all waves done reading buf cc before restage
  }

  if (NCC > 16) writeOut(outY, 2048);
  else          writeOut(outG, 8192);
}

__global__ __launch_bounds__(256, 2) void lstm_gemm(
    const float* __restrict__ Wfh, const float* __restrict__ Wfx, const float* __restrict__ bfp,
    const float* __restrict__ Wih, const float* __restrict__ Wix, const float* __restrict__ bip,
    const float* __restrict__ Woh, const float* __restrict__ Wox, const float* __restrict__ bop,
    const float* __restrict__ Wch, const float* __restrict__ Wcx, const float* __restrict__ bcp,
    const float* __restrict__ Wy,  const float* __restrict__ by,
    float* __restrict__ ws)
{
  __shared__ float  ldsW[4 * 32 * 128];   // 64 KB (ring-4 W chunks, f32)
  __shared__ ushort ldsA[4 * 64 * 32];    // 16 KB (ring-4 A chunks, bf16)

  const int tid  = threadIdx.x;
  const int lane = tid & 63;
  const int widx = tid >> 6;
  const int n    = lane & 31;
  const int j0w  = widx * 32;
  const ushort* Abf = (const ushort*)(ws + ABF_OFF);

  const int bid    = blockIdx.x;          // 0..511
  const int gate   = bid >> 7;
  const int gs     = bid & 127;
  const int stripe = gs >> 3;
  const int ks     = gs & 7;
  const int j0     = stripe * 128;

  const float *Wg_h, *Wg_x, *bg;
  if      (gate == 0) { Wg_h = Wfh; Wg_x = Wfx; bg = bfp; }
  else if (gate == 1) { Wg_h = Wih; Wg_x = Wix; bg = bip; }
  else if (gate == 2) { Wg_h = Wch; Wg_x = Wcx; bg = bcp; }
  else                { Wg_h = Woh; Wg_x = Wox; bg = bop; }

  const float* Wg    = ((ks < 4) ? Wg_h : Wg_x) + j0;
  const int    krow0 = (ks & 3) * 512;
  const int    aK0   = ks * 512;
  const float  biasG = (ks == 0) ? bg[j0 + j0w + n] : 0.f;
  float* outG = ws + GATE_PART + (size_t)ks * 524288 + (size_t)gate * 2048 + j0 + j0w + n;

  if (bid < 128) {   // + y job: ystripe = stripe, yks = ks
    const float* Wyb  = Wy + j0;
    const int    yk0  = ks * 256;
    const float  biasY = (ks == 0) ? by[j0 + j0w + n] : 0.f;
    float* outY = ws + Y_PART + (size_t)ks * 131072 + j0 + j0w + n;
    gemm_job<24>(Wg, krow0, aK0, Wyb, yk0, biasG, biasY, outG, outY,
                 Abf, ldsW, ldsA, lane, widx);
  } else {
    gemm_job<16>(Wg, krow0, aK0, Wg, 0, biasG, 0.f, outG, outG,
                 Abf, ldsW, ldsA, lane, widx);
  }
}

// ---------------------------------------------------------------------------
// Kernel 2: reduce K-split partials, apply LSTM nonlinearity, pack [y|h|c].
// ---------------------------------------------------------------------------
__device__ __forceinline__ float fsigmoid(float x) {
  return 1.f / (1.f + __expf(-x));
}
__device__ __forceinline__ float ftanh(float x) {
  return 1.f - 2.f / (1.f + __expf(2.f * x));
}

__global__ __launch_bounds__(64) void lstm_combine(
    const float* __restrict__ ws, const float* __restrict__ c_prev,
    float* __restrict__ out)
{
  const int t  = blockIdx.x * 64 + threadIdx.x;  // 0..32767
  const int b  = t >> 9;
  const int j4 = (t & 511) * 4;

  f32x4 g[4];
  #pragma unroll
  for (int gg = 0; gg < 4; ++gg) {
    f32x4 s = (f32x4){0.f, 0.f, 0.f, 0.f};
    #pragma unroll
    for (int ks = 0; ks < 8; ++ks)
      s += *(const f32x4*)(ws + GATE_PART + (size_t)ks * 524288 + (size_t)b * 8192 + gg * 2048 + j4);
    g[gg] = s;
  }
  f32x4 ysum = (f32x4){0.f, 0.f, 0.f, 0.f};
  #pragma unroll
  for (int ks = 0; ks < 8; ++ks)
    ysum += *(const f32x4*)(ws + Y_PART + (size_t)ks * 131072 + (size_t)b * 2048 + j4);

  const f32x4 cp = *(const f32x4*)(c_prev + (size_t)b * 2048 + j4);
  f32x4 hF, cF;
  #pragma unroll
  for (int e = 0; e < 4; ++e) {
    float f  = fsigmoid(g[0][e]);
    float i  = fsigmoid(g[1][e]);
    float ct = ftanh(g[2][e]);
    float o  = fsigmoid(g[3][e]);
    float c  = f * cp[e] + i * ct;
    cF[e] = c;
    hF[e] = o * ftanh(c);
  }
  float* ob = out + (size_t)b * 6144;
  *(f32x4*)(ob + j4)        = ysum;   // y = h_prev @ Wy + by
  *(f32x4*)(ob + 2048 + j4) = hF;     // h
  *(f32x4*)(ob + 4096 + j4) = cF;     // c
}

extern "C" void kernel_launch(void* const* d_in, const int* in_sizes, int n_in,
                              void* d_out, int out_size, void* d_ws, size_t ws_size,
                              hipStream_t stream)
{
  const float* X   = (const float*)d_in[0];
  const float* H   = (const float*)d_in[1];
  const float* Cp  = (const float*)d_in[2];
  const float* Wfh = (const float*)d_in[3];
  const float* Wfx = (const float*)d_in[4];
  const float* bfp = (const float*)d_in[5];
  const float* Wih = (const float*)d_in[6];
  const float* Wix = (const float*)d_in[7];
  const float* bip = (const float*)d_in[8];
  const float* Woh = (const float*)d_in[9];
  const float* Wox = (const float*)d_in[10];
  const float* bop = (const float*)d_in[11];
  const float* Wch = (const float*)d_in[12];
  const float* Wcx = (const float*)d_in[13];
  const float* bcp = (const float*)d_in[14];
  const float* Wy  = (const float*)d_in[15];
  const float* by  = (const float*)d_in[16];
  float* ws  = (float*)d_ws;
  float* out = (float*)d_out;

  lstm_aconv<<<128, 256, 0, stream>>>(X, H, (ushort*)(ws + ABF_OFF));
  lstm_gemm<<<512, 256, 0, stream>>>(Wfh, Wfx, bfp, Wih, Wix, bip,
                                     Woh, Wox, bop, Wch, Wcx, bcp, Wy, by, ws);
  lstm_combine<<<512, 64, 0, stream>>>(ws, Cp, out);
}